// Round 15
// baseline (128.469 us; speedup 1.0000x reference)
//
#include <hip/hip_runtime.h>
#include <hip/hip_bf16.h>

// Problem constants
#define BB 2
#define SS 2048
#define DD 1024
#define HH 16
#define MMR (BB*SS)   // 4096 rows
#define ND3 3072      // fused QKV width

typedef __hip_bfloat16 bf;
typedef __bf16 bf16x8 __attribute__((ext_vector_type(8)));
typedef float f32x4 __attribute__((ext_vector_type(4)));
typedef float f32x16 __attribute__((ext_vector_type(16)));

#define VMCNT(n) asm volatile("s_waitcnt vmcnt(" #n ")" ::: "memory")

__device__ __forceinline__ f32x4 mfma16(bf16x8 a, bf16x8 b, f32x4 c) {
    return __builtin_amdgcn_mfma_f32_16x16x32_bf16(a, b, c, 0, 0, 0);
}
__device__ __forceinline__ f32x16 mfma32(bf16x8 a, bf16x8 b, f32x16 c) {
    return __builtin_amdgcn_mfma_f32_32x32x16_bf16(a, b, c, 0, 0, 0);
}
__device__ __forceinline__ unsigned cvt_pk_bf16(float lo, float hi) {
    unsigned r;
    asm("v_cvt_pk_bf16_f32 %0, %1, %2" : "=v"(r) : "v"(lo), "v"(hi));
    return r;
}
// after: a = {a.lo31, b.lo31}, b = {a.hi31, b.hi31}
__device__ __forceinline__ void pl32swap(unsigned& a, unsigned& b) {
    asm("v_permlane32_swap_b32 %0, %1" : "+v"(a), "+v"(b));
}
// async global->LDS, 16B/lane; LDS dest = wave-uniform base + lane*16
__device__ __forceinline__ void glds16(const bf* g, bf* l) {
    __builtin_amdgcn_global_load_lds(
        (const __attribute__((address_space(1))) void*)g,
        (__attribute__((address_space(3))) void*)l,
        16, 0, 0);
}

// ---------------------------------------------------------------
// All f32->bf16 converts in ONE launch. blocks 0..4095: X (4M elems);
// blocks 4096..8191: Wq,Wk,Wv (into Wqkv) and Wo (into Wob), 1M each.
__global__ __launch_bounds__(256) void k_convert(const float* __restrict__ X,
                                                 const float* __restrict__ Wq,
                                                 const float* __restrict__ Wk,
                                                 const float* __restrict__ Wv,
                                                 const float* __restrict__ Wo,
                                                 bf* __restrict__ Xb,
                                                 bf* __restrict__ Wqkv,
                                                 bf* __restrict__ Wob) {
    const int bid = blockIdx.x;
    const float* src;
    bf* dst;
    int off;
    if (bid < 4096) {
        src = X; dst = Xb; off = bid;
    } else {
        const int r = (bid - 4096) >> 10;
        src = (r == 0) ? Wq : (r == 1) ? Wk : (r == 2) ? Wv : Wo;
        dst = (r < 3) ? (Wqkv + (size_t)r * 1048576) : Wob;
        off = (bid - 4096) & 1023;
    }
    const int j = (off * 256 + threadIdx.x) * 4;
    float4 v = *(const float4*)(src + j);
    bf tmp[4];
    tmp[0] = __float2bfloat16(v.x);
    tmp[1] = __float2bfloat16(v.y);
    tmp[2] = __float2bfloat16(v.z);
    tmp[3] = __float2bfloat16(v.w);
    *(uint2*)(dst + j) = *(const uint2*)tmp;
}

// ---------------------------------------------------------------
// QKV GEMM v2: 128x128 tile, BK=32, 8 waves (512 thr), wave = 32x64 quadrant.
// 2-BUFFER pair-unrolled pipeline (even tiles buf0 / odd buf1, both
// COMPILE-TIME -> ds addresses fold to base + offset: immediates), running
// global source pointers (+32 elems/tile). 32KB LDS -> 4 blocks/CU x 8 waves
// = 32 waves/CU (hw cap). seg-XOR swizzle (0-conflict, r6-verified).
// Fused epilogue: cols<2048 -> per-head L2-norm * mask -> Qn/Kn [B*H,S,64];
// cols>=2048 -> transposed bf16 write to Vt [B*H,64,S].
__global__ __launch_bounds__(512, 8) void k_gemm8(const bf* __restrict__ A,
                                                  const bf* __restrict__ Bt,
                                                  const int* __restrict__ masks,
                                                  bf* __restrict__ Qn,
                                                  bf* __restrict__ Kn,
                                                  bf* __restrict__ Vt,
                                                  int nx, int K) {
    __shared__ __align__(16) bf Asm[2][128 * 32];   // 16KB
    __shared__ __align__(16) bf Bsm[2][128 * 32];   // 16KB
    const int tid = threadIdx.x;
    const int w = tid >> 6, lane = tid & 63, g = lane >> 4, rl = lane & 15;
    const int cpx = gridDim.x >> 3;
    const int swz = (blockIdx.x & 7) * cpx + (blockIdx.x >> 3);
    const int m0 = (swz / nx) * 128, n0 = (swz % nx) * 128;
    const int wr = (w >> 1) * 32, wc = (w & 1) * 64;
    const int lrow = lane >> 2, lseg = lane & 3;
    const int xseg = lseg ^ ((lrow >> 1) & 3);   // pre-swizzled source seg

    f32x4 acc[2][4] = {};

    // running source pointers (strength-reduced): +32 elems per K-tile
    const bf* asr = A + (size_t)(m0 + w * 16 + lrow) * K + xseg * 8;
    const bf* bsr = Bt + (size_t)(n0 + w * 16 + lrow) * K + xseg * 8;
    bf* const adst = &Asm[0][w * 512];
    bf* const bdst = &Bsm[0][w * 512];

    auto stageP = [&](int buf) {     // buf is compile-time at each call site
        glds16(asr, adst + buf * 4096);
        glds16(bsr, bdst + buf * 4096);
        asr += 32; bsr += 32;
    };

    auto computeT = [&](const bf* Ab, const bf* Bb) {
        bf16x8 af[2], bfr[4];
#pragma unroll
        for (int m = 0; m < 2; ++m) {
            const int row = wr + m * 16 + rl;
            af[m] = __builtin_bit_cast(bf16x8,
                *(const int4*)&Ab[row * 32 + (g ^ ((row >> 1) & 3)) * 8]);
        }
#pragma unroll
        for (int n = 0; n < 4; ++n) {
            const int row = wc + n * 16 + rl;
            bfr[n] = __builtin_bit_cast(bf16x8,
                *(const int4*)&Bb[row * 32 + (g ^ ((row >> 1) & 3)) * 8]);
        }
        __builtin_amdgcn_s_setprio(1);
#pragma unroll
        for (int m = 0; m < 2; ++m)
#pragma unroll
            for (int n = 0; n < 4; ++n)
                acc[m][n] = mfma16(af[m], bfr[n], acc[m][n]);
        __builtin_amdgcn_s_setprio(0);
    };

    const int T = K >> 5;            // 32 (even)
    stageP(0);                       // tile 0
    __syncthreads();
    for (int t = 0; t < T; t += 2) {
        stageP(1);                   // tile t+1 -> buf1
        computeT(&Asm[0][0], &Bsm[0][0]);    // tile t
        __syncthreads();
        if (t + 2 < T) stageP(0);    // tile t+2 -> buf0
        computeT(&Asm[1][0], &Bsm[1][0]);    // tile t+1
        __syncthreads();
    }

    const int ncol0 = n0 + wc;   // wave's 64-col base == one head slice
    if (ncol0 < 2048) {
        bf* dst = (ncol0 < 1024) ? Qn : Kn;
        const int h2 = (ncol0 >> 6) & 15;
#pragma unroll
        for (int m = 0; m < 2; ++m) {
#pragma unroll
            for (int ri = 0; ri < 4; ++ri) {
                const int row = m0 + wr + m * 16 + g * 4 + ri;   // b*S+s
                float ss = 0.f;
#pragma unroll
                for (int n = 0; n < 4; ++n) ss += acc[m][n][ri] * acc[m][n][ri];
#pragma unroll
                for (int d = 1; d < 16; d <<= 1) ss += __shfl_xor(ss, d, 64);
                const float sc = rsqrtf(ss) * (masks[row] ? 1.0f : 0.0f);
                const int b = row >> 11, s = row & 2047;
                const size_t base = ((size_t)(b * HH + h2) * SS + s) * 64;
#pragma unroll
                for (int n = 0; n < 4; ++n)
                    dst[base + n * 16 + rl] = __float2bfloat16(acc[m][n][ri] * sc);
            }
        }
    } else {
        // fused V transpose: Vt[(b*H+h)*64 + d][s], packed 4-bf16 writes
        const int h2 = (ncol0 - 2048) >> 6;
        const int b = (m0 + wr) >> 11;
        const int sb = ((m0 + wr) & 2047) + g * 4;
#pragma unroll
        for (int m = 0; m < 2; ++m)
#pragma unroll
            for (int n = 0; n < 4; ++n) {
                const int d = n * 16 + rl;
                bf t4[4];
#pragma unroll
                for (int ri = 0; ri < 4; ++ri) t4[ri] = __float2bfloat16(acc[m][n][ri]);
                *(uint2*)&Vt[((size_t)(b * HH + h2) * 64 + d) * SS + sb + m * 16] =
                    *(uint2*)t4;
            }
    }
}

// ---------------------------------------------------------------
// Out-proj GEMM: 64x128 tile, BK=32, 4 waves, 3-buffer counted-vmcnt pipeline.
__global__ __launch_bounds__(256) void k_gemm(const bf* __restrict__ A,
                                              const bf* __restrict__ Bt,
                                              float* __restrict__ Cf,
                                              int nx, int N, int K) {
    constexpr int BM = 64, BN = 128;
    __shared__ __align__(16) bf Asm[3][BM * 32];
    __shared__ __align__(16) bf Bsm[3][BN * 32];
    const int tid = threadIdx.x;
    const int w = tid >> 6, lane = tid & 63, g = lane >> 4, rl = lane & 15;
    const int cpx = gridDim.x >> 3;
    const int swz = (blockIdx.x & 7) * cpx + (blockIdx.x >> 3);
    const int m0 = (swz / nx) * BM, n0 = (swz % nx) * BN;
    const int wr = (w >> 1) * 32, wc = (w & 1) * 64;
    const int lrow = lane >> 2, lseg = lane & 3;
    const int xseg = lseg ^ ((lrow >> 1) & 3);

    f32x4 acc[2][4] = {};
    const bf* Ap = A + (size_t)m0 * K;
    const bf* Bp = Bt + (size_t)n0 * K;

    auto stage = [&](int bi, int k0) {
        glds16(Ap + (size_t)(w * 16 + lrow) * K + k0 + xseg * 8, &Asm[bi][w * 512]);
#pragma unroll
        for (int u = 0; u < 2; ++u)
            glds16(Bp + (size_t)(u * 64 + w * 16 + lrow) * K + k0 + xseg * 8,
                   &Bsm[bi][(u * 64 + w * 16) * 32]);
    };

    const int T = K >> 5;
    stage(0, 0);
    stage(1, 32);
    int cur = 0, nxt = 2;
    for (int t = 0; t < T; ++t) {
        __builtin_amdgcn_sched_barrier(0);
        if (t < T - 1) { VMCNT(3); } else { VMCNT(0); }
        __builtin_amdgcn_s_barrier();
        __builtin_amdgcn_sched_barrier(0);
        if (t + 2 < T) stage(nxt, (t + 2) * 32);

        const bf* Ab = Asm[cur];
        const bf* Bb = Bsm[cur];
        bf16x8 af[2], bfr[4];
#pragma unroll
        for (int m = 0; m < 2; ++m) {
            const int row = wr + m * 16 + rl;
            af[m] = __builtin_bit_cast(bf16x8,
                *(const int4*)&Ab[row * 32 + (g ^ ((row >> 1) & 3)) * 8]);
        }
#pragma unroll
        for (int n = 0; n < 4; ++n) {
            const int row = wc + n * 16 + rl;
            bfr[n] = __builtin_bit_cast(bf16x8,
                *(const int4*)&Bb[row * 32 + (g ^ ((row >> 1) & 3)) * 8]);
        }
        __builtin_amdgcn_s_setprio(1);
#pragma unroll
        for (int m = 0; m < 2; ++m)
#pragma unroll
            for (int n = 0; n < 4; ++n)
                acc[m][n] = mfma16(af[m], bfr[n], acc[m][n]);
        __builtin_amdgcn_s_setprio(0);

        cur = (cur == 2) ? 0 : cur + 1;
        nxt = (nxt == 2) ? 0 : nxt + 1;
    }

#pragma unroll
    for (int m = 0; m < 2; ++m)
#pragma unroll
        for (int n = 0; n < 4; ++n)
#pragma unroll
            for (int ri = 0; ri < 4; ++ri)
                Cf[(size_t)(m0 + wr + m * 16 + g * 4 + ri) * N + n0 + wc + n * 16 + rl] =
                    acc[m][n][ri];
}

// ---------------------------------------------------------------
// Attention v7 (r14-proven, ~33us): r10 algorithm with VALU-lean loop.
// Pair-unrolled so the LDS buffer index is COMPILE-TIME in each half;
// staging uses running global pointers. In-register P via cvt_pk +
// permlane32_swap; kp-partials summed via one-time LDS reduce.
__global__ __launch_bounds__(256) void k_attn(const bf* __restrict__ Qn,  // [B*H,S,64]
                                              const bf* __restrict__ Kn,  // [B*H,S,64]
                                              const bf* __restrict__ Vt,  // [B*H,64,S]
                                              bf* __restrict__ Ctx) {     // [B*S, D]
    __shared__ __align__(16) bf Ksm[2][64 * 64];  // [kv][d], 16KB
    __shared__ __align__(16) bf Vsm[2][64 * 64];  // [d][kv], 16KB

    const int idx = blockIdx.x;
    const int qt = 31 - (idx >> 5);       // 0..31, largest-first (LPT)
    const int by = idx & 31;              // b*H + h
    const int b = by >> 4, h = by & 15;
    const int tid = threadIdx.x;
    const int w = tid >> 6, lane = tid & 63;
    const int l31 = lane & 31, hl = lane >> 5;
    const int qh = w >> 1;                // q-half: rows qt*64+qh*32 ..+32
    const int kp = w & 1;                 // k-parity: handles subtile kb=t*64+kp*32
    const int qw = qt * 64 + qh * 32;
    const int qg = qw + l31;

    const bf* Qp = Qn + (size_t)by * SS * 64;
    const bf* Kp = Kn + (size_t)by * SS * 64;
    const bf* Vp = Vt + (size_t)by * 64 * SS;

    // hoisted Q (B-operand): col=q=l31, d = st*16 + hl*8 + 0..7
    bf16x8 aqs[4];
#pragma unroll
    for (int st = 0; st < 4; ++st)
        aqs[st] = __builtin_bit_cast(bf16x8,
            *(const int4*)(Qp + (size_t)(qw + l31) * 64 + st * 16 + hl * 8));

    // staging: chunk c = w*2+u = 8 rows x 128B; pre-swizzled source slot
    const int srow = lane >> 3;
    const int sblk = (lane & 7) ^ srow;

    // running source pointers (strength-reduced): tile t adds 4096 (K) / 64 (V)
    const bf* ksr = Kp + (size_t)(w * 16 + srow) * 64 + sblk * 8;   // chunk w*2, u=0
    const bf* vsr = Vp + (size_t)(w * 16 + srow) * SS + sblk * 8;
    bf* const kdst = &Ksm[0][w * 1024];    // chunks w*2, w*2+1 (u offset +512)
    bf* const vdst = &Vsm[0][w * 1024];

    auto stageP = [&](int buf, const bf* ks, const bf* vs) {
        glds16(ks,            kdst + buf * 4096);
        glds16(ks + 512,      kdst + buf * 4096 + 512);     // u=1: +8 K-rows
        glds16(vs,            vdst + buf * 4096);
        glds16(vs + 8 * SS,   vdst + buf * 4096 + 512);     // u=1: +8 d-rows
    };

    f32x16 accd[2] = {};

    // per-tile compute; Ks/Vs are compile-time buffer bases at each call site
    auto doTile = [&](const bf* Ks, const bf* Vs, int t) {
        const int kb = t * 64 + kp * 32;
        if (kb > qw + 31) return;
        // ---- QK^T (swapped): D[row=k][col=q]
        f32x16 pc = {};
        const int r = kp * 32 + l31;
#pragma unroll
        for (int st = 0; st < 4; ++st) {
            bf16x8 ak = __builtin_bit_cast(bf16x8,
                *(const int4*)&Ks[r * 64 + (((2 * st + hl) ^ (r & 7)) << 3)]);
            pc = mfma32(ak, aqs[st], pc);
        }
        // ---- relu + causal (elementwise only near diagonal)
        const bool dg = (kb + 31 > qw);
        float pv[16];
#pragma unroll
        for (int m2 = 0; m2 < 16; ++m2) {
            float v = fmaxf(pc[m2], 0.0f);
            if (dg) {
                const int kg = kb + (m2 & 3) + 8 * (m2 >> 2) + 4 * hl;
                if (kg > qg) v = 0.0f;
            }
            pv[m2] = v;
        }
        // ---- pack to bf16 pairs + permlane swaps -> PV A-frags (no LDS)
        unsigned P[8];
#pragma unroll
        for (int m2 = 0; m2 < 8; ++m2) P[m2] = cvt_pk_bf16(pv[2 * m2], pv[2 * m2 + 1]);
        pl32swap(P[0], P[2]);
        pl32swap(P[1], P[3]);
        pl32swap(P[4], P[6]);
        pl32swap(P[5], P[7]);
        // ---- PV: D[row=q][col=d]
#pragma unroll
        for (int s = 0; s < 2; ++s) {
            uint4 pw = {P[4 * s + 0], P[4 * s + 1], P[4 * s + 2], P[4 * s + 3]};
            bf16x8 pa = __builtin_bit_cast(bf16x8, pw);
#pragma unroll
            for (int dt = 0; dt < 2; ++dt) {
                const int d = dt * 32 + l31;
                const int slot = kp * 4 + s * 2 + hl;
                bf16x8 bv = __builtin_bit_cast(bf16x8,
                    *(const int4*)&Vs[d * 64 + ((slot ^ (d & 7)) << 3)]);
                accd[dt] = mfma32(pa, bv, accd[dt]);
            }
        }
    };

    // prologue: tile 0 into buffer 0
    stageP(0, ksr, vsr);
    ksr += 4096; vsr += 64;
    __syncthreads();

    // pair-unrolled loop: buffer0 = even tiles, buffer1 = odd tiles
    int t = 0;
    while (t + 1 <= qt) {
        // A: compute buffer0 (tile t), prefetch tile t+1 into buffer1
        stageP(1, ksr, vsr);
        ksr += 4096; vsr += 64;
        doTile(&Ksm[0][0], &Vsm[0][0], t);
        __syncthreads();
        // B: compute buffer1 (tile t+1), prefetch tile t+2 into buffer0
        if (t + 2 <= qt) {
            stageP(0, ksr, vsr);
            ksr += 4096; vsr += 64;
        }
        doTile(&Ksm[1][0], &Vsm[1][0], t + 1);
        __syncthreads();
        t += 2;
    }
    if (t <= qt) {                        // even qt tail: tile t in buffer0
        doTile(&Ksm[0][0], &Vsm[0][0], t);
        __syncthreads();
    }

    // ---- cross-wave (k-parity) reduce via LDS, then kp==0 writes Ctx
    float* red = (float*)&Ksm[0][0];      // 16KB: 2 q-halves x 8KB
    if (kp == 1) {
#pragma unroll
        for (int dt = 0; dt < 2; ++dt)
#pragma unroll
            for (int m2 = 0; m2 < 16; ++m2)
                red[qh * 2048 + (dt * 16 + m2) * 64 + lane] = accd[dt][m2];
    }
    __syncthreads();
    if (kp == 0) {
#pragma unroll
        for (int dt = 0; dt < 2; ++dt)
#pragma unroll
            for (int m2 = 0; m2 < 16; ++m2) {
                const float v = accd[dt][m2] + red[qh * 2048 + (dt * 16 + m2) * 64 + lane];
                const int q = qw + (m2 & 3) + 8 * (m2 >> 2) + 4 * hl;
                const int d = dt * 32 + l31;
                Ctx[(size_t)(b * SS + q) * DD + h * 64 + d] = __float2bfloat16(v);
            }
    }
}

// ---------------------------------------------------------------
extern "C" void kernel_launch(void* const* d_in, const int* in_sizes, int n_in,
                              void* d_out, int out_size, void* d_ws, size_t ws_size,
                              hipStream_t stream) {
    const float* X  = (const float*)d_in[0];
    const int* masks = (const int*)d_in[1];
    const float* Wq = (const float*)d_in[2];
    const float* Wk = (const float*)d_in[3];
    const float* Wv = (const float*)d_in[4];
    const float* Wo = (const float*)d_in[5];
    float* out = (float*)d_out;
    char* ws = (char*)d_ws;

    const size_t MB = 1024 * 1024;
    bf* Xb   = (bf*)(ws);              // 8 MB  [B*S, D]
    bf* Wqkv = (bf*)(ws + 8  * MB);    // 6 MB  [3072, 1024]
    bf* Wob  = (bf*)(ws + 14 * MB);    // 2 MB
    bf* Qn   = (bf*)(ws + 16 * MB);    // 8 MB  [B*H, S, 64]
    bf* Kn   = (bf*)(ws + 24 * MB);
    bf* Vt   = (bf*)(ws + 32 * MB);    // 8 MB  [B*H, 64, S]
    bf* Ctx  = (bf*)(ws + 40 * MB);    // 8 MB  [B*S, D]

    // converts (one launch)
    k_convert<<<8192, 256, 0, stream>>>(X, Wq, Wk, Wv, Wo, Xb, Wqkv, Wob);

    // fused QKV projection + norm/mask epilogue + V-transpose
    // (128x128 tiles -> 768 blocks, 8 waves, 2-buffer pair-unrolled)
    k_gemm8<<<(ND3 / 128) * (MMR / 128), 512, 0, stream>>>(
        Xb, Wqkv, masks, Qn, Kn, Vt, ND3 / 128, DD);

    // attention (r14 VALU-lean pair-unrolled loop)
    k_attn<<<1024, 256, 0, stream>>>(Qn, Kn, Vt, Ctx);

    // output projection (64x128 tiles -> 512 blocks)
    k_gemm<<<(DD / 128) * (MMR / 64), 256, 0, stream>>>(
        Ctx, Wob, out, DD / 128, DD, DD);
}

// Round 16
// 94.857 us; speedup vs baseline: 1.3543x; 1.3543x over previous
//
#include <hip/hip_runtime.h>
#include <hip/hip_bf16.h>

// Problem constants
#define BB 2
#define SS 2048
#define DD 1024
#define HH 16
#define MMR (BB*SS)   // 4096 rows
#define ND3 3072      // fused QKV width

typedef __hip_bfloat16 bf;
typedef __bf16 bf16x8 __attribute__((ext_vector_type(8)));
typedef float f32x4 __attribute__((ext_vector_type(4)));
typedef float f32x16 __attribute__((ext_vector_type(16)));

#define VMCNT(n) asm volatile("s_waitcnt vmcnt(" #n ")" ::: "memory")

__device__ __forceinline__ f32x4 mfma16(bf16x8 a, bf16x8 b, f32x4 c) {
    return __builtin_amdgcn_mfma_f32_16x16x32_bf16(a, b, c, 0, 0, 0);
}
__device__ __forceinline__ f32x16 mfma32(bf16x8 a, bf16x8 b, f32x16 c) {
    return __builtin_amdgcn_mfma_f32_32x32x16_bf16(a, b, c, 0, 0, 0);
}
__device__ __forceinline__ unsigned cvt_pk_bf16(float lo, float hi) {
    unsigned r;
    asm("v_cvt_pk_bf16_f32 %0, %1, %2" : "=v"(r) : "v"(lo), "v"(hi));
    return r;
}
// after: a = {a.lo31, b.lo31}, b = {a.hi31, b.hi31}
__device__ __forceinline__ void pl32swap(unsigned& a, unsigned& b) {
    asm("v_permlane32_swap_b32 %0, %1" : "+v"(a), "+v"(b));
}
// async global->LDS, 16B/lane; LDS dest = wave-uniform base + lane*16
__device__ __forceinline__ void glds16(const bf* g, bf* l) {
    __builtin_amdgcn_global_load_lds(
        (const __attribute__((address_space(1))) void*)g,
        (__attribute__((address_space(3))) void*)l,
        16, 0, 0);
}

// ---------------------------------------------------------------
// All f32->bf16 converts in ONE launch. blocks 0..4095: X (4M elems);
// blocks 4096..8191: Wq,Wk,Wv (into Wqkv) and Wo (into Wob), 1M each.
__global__ __launch_bounds__(256) void k_convert(const float* __restrict__ X,
                                                 const float* __restrict__ Wq,
                                                 const float* __restrict__ Wk,
                                                 const float* __restrict__ Wv,
                                                 const float* __restrict__ Wo,
                                                 bf* __restrict__ Xb,
                                                 bf* __restrict__ Wqkv,
                                                 bf* __restrict__ Wob) {
    const int bid = blockIdx.x;
    const float* src;
    bf* dst;
    int off;
    if (bid < 4096) {
        src = X; dst = Xb; off = bid;
    } else {
        const int r = (bid - 4096) >> 10;
        src = (r == 0) ? Wq : (r == 1) ? Wk : (r == 2) ? Wv : Wo;
        dst = (r < 3) ? (Wqkv + (size_t)r * 1048576) : Wob;
        off = (bid - 4096) & 1023;
    }
    const int j = (off * 256 + threadIdx.x) * 4;
    float4 v = *(const float4*)(src + j);
    bf tmp[4];
    tmp[0] = __float2bfloat16(v.x);
    tmp[1] = __float2bfloat16(v.y);
    tmp[2] = __float2bfloat16(v.z);
    tmp[3] = __float2bfloat16(v.w);
    *(uint2*)(dst + j) = *(const uint2*)tmp;
}

// ---------------------------------------------------------------
// QKV GEMM v3: r14's proven 3-buffer counted-vmcnt pipeline (40.4us) with
// the K-loop UNROLLED BY 3 so the mod-3 buffer indices are compile-time
// ((cur,nxt) cycles (0,2),(1,0),(2,1)) -> ds/stage addresses fold to
// base + offset: immediates; running global source pointers (+32/step).
// Sync semantics identical to r14: VMCNT(2) (VMCNT(0) at last step) then
// raw s_barrier, stage after barrier. launch_bounds(512,6) as r14 (the
// r15 (512,8) variant spilled: VGPR 32, WRITE_SIZE 120MB).
// Fused epilogue: cols<2048 -> per-head L2-norm * mask -> Qn/Kn [B*H,S,64];
// cols>=2048 -> transposed bf16 write to Vt [B*H,64,S]. K fixed = 1024.
__global__ __launch_bounds__(512, 6) void k_gemm8(const bf* __restrict__ A,
                                                  const bf* __restrict__ Bt,
                                                  const int* __restrict__ masks,
                                                  bf* __restrict__ Qn,
                                                  bf* __restrict__ Kn,
                                                  bf* __restrict__ Vt,
                                                  int nx) {
    constexpr int K = 1024;
    constexpr int T = K >> 5;        // 32 K-steps
    __shared__ __align__(16) bf Asm[3][128 * 32];
    __shared__ __align__(16) bf Bsm[3][128 * 32];
    const int tid = threadIdx.x;
    const int w = tid >> 6, lane = tid & 63, g = lane >> 4, rl = lane & 15;
    const int cpx = gridDim.x >> 3;
    const int swz = (blockIdx.x & 7) * cpx + (blockIdx.x >> 3);
    const int m0 = (swz / nx) * 128, n0 = (swz % nx) * 128;
    const int wr = (w >> 1) * 32, wc = (w & 1) * 64;
    const int lrow = lane >> 2, lseg = lane & 3;
    const int xseg = lseg ^ ((lrow >> 1) & 3);   // pre-swizzled source seg

    f32x4 acc[2][4] = {};

    // running source pointers (strength-reduced): +32 elems per K-step
    const bf* asr = A + (size_t)(m0 + w * 16 + lrow) * K + xseg * 8;
    const bf* bsr = Bt + (size_t)(n0 + w * 16 + lrow) * K + xseg * 8;
    bf* const adst = &Asm[0][w * 512];
    bf* const bdst = &Bsm[0][w * 512];

    auto stageP = [&](int buf) {     // buf is compile-time at every call site
        glds16(asr, adst + buf * 4096);
        glds16(bsr, bdst + buf * 4096);
        asr += 32; bsr += 32;
    };

    auto computeT = [&](const bf* Ab, const bf* Bb) {
        bf16x8 af[2], bfr[4];
#pragma unroll
        for (int m = 0; m < 2; ++m) {
            const int row = wr + m * 16 + rl;
            af[m] = __builtin_bit_cast(bf16x8,
                *(const int4*)&Ab[row * 32 + (g ^ ((row >> 1) & 3)) * 8]);
        }
#pragma unroll
        for (int n = 0; n < 4; ++n) {
            const int row = wc + n * 16 + rl;
            bfr[n] = __builtin_bit_cast(bf16x8,
                *(const int4*)&Bb[row * 32 + (g ^ ((row >> 1) & 3)) * 8]);
        }
        __builtin_amdgcn_s_setprio(1);
#pragma unroll
        for (int m = 0; m < 2; ++m)
#pragma unroll
            for (int n = 0; n < 4; ++n)
                acc[m][n] = mfma16(af[m], bfr[n], acc[m][n]);
        __builtin_amdgcn_s_setprio(0);
    };

    // step(CUR, NXT, t): r14 semantics, buffer indices compile-time
    auto step = [&](auto CURc, auto NXTc, int t) {
        constexpr int CUR = decltype(CURc)::value;
        constexpr int NXT = decltype(NXTc)::value;
        __builtin_amdgcn_sched_barrier(0);
        if (t < T - 1) { VMCNT(2); } else { VMCNT(0); }
        __builtin_amdgcn_s_barrier();     // staged loads stay in flight
        __builtin_amdgcn_sched_barrier(0);
        if (t + 2 < T) stageP(NXT);
        computeT(&Asm[CUR][0], &Bsm[CUR][0]);
    };
    using c0 = std::integral_constant<int, 0>;
    using c1 = std::integral_constant<int, 1>;
    using c2 = std::integral_constant<int, 2>;

    stageP(0);                       // tile 0
    stageP(1);                       // tile 1
    // 32 steps = 10 x (0,2)(1,0)(2,1) + steps 30 (0,2), 31 (1,0)
#pragma unroll 1
    for (int t = 0; t < 30; t += 3) {
        step(c0{}, c2{}, t);
        step(c1{}, c0{}, t + 1);
        step(c2{}, c1{}, t + 2);
    }
    step(c0{}, c2{}, 30);
    step(c1{}, c0{}, 31);

    const int ncol0 = n0 + wc;   // wave's 64-col base == one head slice
    if (ncol0 < 2048) {
        bf* dst = (ncol0 < 1024) ? Qn : Kn;
        const int h2 = (ncol0 >> 6) & 15;
#pragma unroll
        for (int m = 0; m < 2; ++m) {
#pragma unroll
            for (int ri = 0; ri < 4; ++ri) {
                const int row = m0 + wr + m * 16 + g * 4 + ri;   // b*S+s
                float ss = 0.f;
#pragma unroll
                for (int n = 0; n < 4; ++n) ss += acc[m][n][ri] * acc[m][n][ri];
#pragma unroll
                for (int d = 1; d < 16; d <<= 1) ss += __shfl_xor(ss, d, 64);
                const float sc = rsqrtf(ss) * (masks[row] ? 1.0f : 0.0f);
                const int b = row >> 11, s = row & 2047;
                const size_t base = ((size_t)(b * HH + h2) * SS + s) * 64;
#pragma unroll
                for (int n = 0; n < 4; ++n)
                    dst[base + n * 16 + rl] = __float2bfloat16(acc[m][n][ri] * sc);
            }
        }
    } else {
        // fused V transpose: Vt[(b*H+h)*64 + d][s], packed 4-bf16 writes
        const int h2 = (ncol0 - 2048) >> 6;
        const int b = (m0 + wr) >> 11;
        const int sb = ((m0 + wr) & 2047) + g * 4;
#pragma unroll
        for (int m = 0; m < 2; ++m)
#pragma unroll
            for (int n = 0; n < 4; ++n) {
                const int d = n * 16 + rl;
                bf t4[4];
#pragma unroll
                for (int ri = 0; ri < 4; ++ri) t4[ri] = __float2bfloat16(acc[m][n][ri]);
                *(uint2*)&Vt[((size_t)(b * HH + h2) * 64 + d) * SS + sb + m * 16] =
                    *(uint2*)t4;
            }
    }
}

// ---------------------------------------------------------------
// Out-proj GEMM: 64x128 tile, BK=32, 4 waves, 3-buffer counted-vmcnt pipeline.
__global__ __launch_bounds__(256) void k_gemm(const bf* __restrict__ A,
                                              const bf* __restrict__ Bt,
                                              float* __restrict__ Cf,
                                              int nx, int N, int K) {
    constexpr int BM = 64, BN = 128;
    __shared__ __align__(16) bf Asm[3][BM * 32];
    __shared__ __align__(16) bf Bsm[3][BN * 32];
    const int tid = threadIdx.x;
    const int w = tid >> 6, lane = tid & 63, g = lane >> 4, rl = lane & 15;
    const int cpx = gridDim.x >> 3;
    const int swz = (blockIdx.x & 7) * cpx + (blockIdx.x >> 3);
    const int m0 = (swz / nx) * BM, n0 = (swz % nx) * BN;
    const int wr = (w >> 1) * 32, wc = (w & 1) * 64;
    const int lrow = lane >> 2, lseg = lane & 3;
    const int xseg = lseg ^ ((lrow >> 1) & 3);

    f32x4 acc[2][4] = {};
    const bf* Ap = A + (size_t)m0 * K;
    const bf* Bp = Bt + (size_t)n0 * K;

    auto stage = [&](int bi, int k0) {
        glds16(Ap + (size_t)(w * 16 + lrow) * K + k0 + xseg * 8, &Asm[bi][w * 512]);
#pragma unroll
        for (int u = 0; u < 2; ++u)
            glds16(Bp + (size_t)(u * 64 + w * 16 + lrow) * K + k0 + xseg * 8,
                   &Bsm[bi][(u * 64 + w * 16) * 32]);
    };

    const int T = K >> 5;
    stage(0, 0);
    stage(1, 32);
    int cur = 0, nxt = 2;
    for (int t = 0; t < T; ++t) {
        __builtin_amdgcn_sched_barrier(0);
        if (t < T - 1) { VMCNT(3); } else { VMCNT(0); }
        __builtin_amdgcn_s_barrier();
        __builtin_amdgcn_sched_barrier(0);
        if (t + 2 < T) stage(nxt, (t + 2) * 32);

        const bf* Ab = Asm[cur];
        const bf* Bb = Bsm[cur];
        bf16x8 af[2], bfr[4];
#pragma unroll
        for (int m = 0; m < 2; ++m) {
            const int row = wr + m * 16 + rl;
            af[m] = __builtin_bit_cast(bf16x8,
                *(const int4*)&Ab[row * 32 + (g ^ ((row >> 1) & 3)) * 8]);
        }
#pragma unroll
        for (int n = 0; n < 4; ++n) {
            const int row = wc + n * 16 + rl;
            bfr[n] = __builtin_bit_cast(bf16x8,
                *(const int4*)&Bb[row * 32 + (g ^ ((row >> 1) & 3)) * 8]);
        }
        __builtin_amdgcn_s_setprio(1);
#pragma unroll
        for (int m = 0; m < 2; ++m)
#pragma unroll
            for (int n = 0; n < 4; ++n)
                acc[m][n] = mfma16(af[m], bfr[n], acc[m][n]);
        __builtin_amdgcn_s_setprio(0);

        cur = (cur == 2) ? 0 : cur + 1;
        nxt = (nxt == 2) ? 0 : nxt + 1;
    }

#pragma unroll
    for (int m = 0; m < 2; ++m)
#pragma unroll
        for (int n = 0; n < 4; ++n)
#pragma unroll
            for (int ri = 0; ri < 4; ++ri)
                Cf[(size_t)(m0 + wr + m * 16 + g * 4 + ri) * N + n0 + wc + n * 16 + rl] =
                    acc[m][n][ri];
}

// ---------------------------------------------------------------
// Attention v7 (r14-proven, ~33us): r10 algorithm with VALU-lean loop.
// Pair-unrolled so the LDS buffer index is COMPILE-TIME in each half;
// staging uses running global pointers. In-register P via cvt_pk +
// permlane32_swap; kp-partials summed via one-time LDS reduce.
__global__ __launch_bounds__(256) void k_attn(const bf* __restrict__ Qn,  // [B*H,S,64]
                                              const bf* __restrict__ Kn,  // [B*H,S,64]
                                              const bf* __restrict__ Vt,  // [B*H,64,S]
                                              bf* __restrict__ Ctx) {     // [B*S, D]
    __shared__ __align__(16) bf Ksm[2][64 * 64];  // [kv][d], 16KB
    __shared__ __align__(16) bf Vsm[2][64 * 64];  // [d][kv], 16KB

    const int idx = blockIdx.x;
    const int qt = 31 - (idx >> 5);       // 0..31, largest-first (LPT)
    const int by = idx & 31;              // b*H + h
    const int b = by >> 4, h = by & 15;
    const int tid = threadIdx.x;
    const int w = tid >> 6, lane = tid & 63;
    const int l31 = lane & 31, hl = lane >> 5;
    const int qh = w >> 1;                // q-half: rows qt*64+qh*32 ..+32
    const int kp = w & 1;                 // k-parity: handles subtile kb=t*64+kp*32
    const int qw = qt * 64 + qh * 32;
    const int qg = qw + l31;

    const bf* Qp = Qn + (size_t)by * SS * 64;
    const bf* Kp = Kn + (size_t)by * SS * 64;
    const bf* Vp = Vt + (size_t)by * 64 * SS;

    // hoisted Q (B-operand): col=q=l31, d = st*16 + hl*8 + 0..7
    bf16x8 aqs[4];
#pragma unroll
    for (int st = 0; st < 4; ++st)
        aqs[st] = __builtin_bit_cast(bf16x8,
            *(const int4*)(Qp + (size_t)(qw + l31) * 64 + st * 16 + hl * 8));

    // staging: chunk c = w*2+u = 8 rows x 128B; pre-swizzled source slot
    const int srow = lane >> 3;
    const int sblk = (lane & 7) ^ srow;

    // running source pointers (strength-reduced): tile t adds 4096 (K) / 64 (V)
    const bf* ksr = Kp + (size_t)(w * 16 + srow) * 64 + sblk * 8;   // chunk w*2, u=0
    const bf* vsr = Vp + (size_t)(w * 16 + srow) * SS + sblk * 8;
    bf* const kdst = &Ksm[0][w * 1024];    // chunks w*2, w*2+1 (u offset +512)
    bf* const vdst = &Vsm[0][w * 1024];

    auto stageP = [&](int buf, const bf* ks, const bf* vs) {
        glds16(ks,            kdst + buf * 4096);
        glds16(ks + 512,      kdst + buf * 4096 + 512);     // u=1: +8 K-rows
        glds16(vs,            vdst + buf * 4096);
        glds16(vs + 8 * SS,   vdst + buf * 4096 + 512);     // u=1: +8 d-rows
    };

    f32x16 accd[2] = {};

    // per-tile compute; Ks/Vs are compile-time buffer bases at each call site
    auto doTile = [&](const bf* Ks, const bf* Vs, int t) {
        const int kb = t * 64 + kp * 32;
        if (kb > qw + 31) return;
        // ---- QK^T (swapped): D[row=k][col=q]
        f32x16 pc = {};
        const int r = kp * 32 + l31;
#pragma unroll
        for (int st = 0; st < 4; ++st) {
            bf16x8 ak = __builtin_bit_cast(bf16x8,
                *(const int4*)&Ks[r * 64 + (((2 * st + hl) ^ (r & 7)) << 3)]);
            pc = mfma32(ak, aqs[st], pc);
        }
        // ---- relu + causal (elementwise only near diagonal)
        const bool dg = (kb + 31 > qw);
        float pv[16];
#pragma unroll
        for (int m2 = 0; m2 < 16; ++m2) {
            float v = fmaxf(pc[m2], 0.0f);
            if (dg) {
                const int kg = kb + (m2 & 3) + 8 * (m2 >> 2) + 4 * hl;
                if (kg > qg) v = 0.0f;
            }
            pv[m2] = v;
        }
        // ---- pack to bf16 pairs + permlane swaps -> PV A-frags (no LDS)
        unsigned P[8];
#pragma unroll
        for (int m2 = 0; m2 < 8; ++m2) P[m2] = cvt_pk_bf16(pv[2 * m2], pv[2 * m2 + 1]);
        pl32swap(P[0], P[2]);
        pl32swap(P[1], P[3]);
        pl32swap(P[4], P[6]);
        pl32swap(P[5], P[7]);
        // ---- PV: D[row=q][col=d]
#pragma unroll
        for (int s = 0; s < 2; ++s) {
            uint4 pw = {P[4 * s + 0], P[4 * s + 1], P[4 * s + 2], P[4 * s + 3]};
            bf16x8 pa = __builtin_bit_cast(bf16x8, pw);
#pragma unroll
            for (int dt = 0; dt < 2; ++dt) {
                const int d = dt * 32 + l31;
                const int slot = kp * 4 + s * 2 + hl;
                bf16x8 bv = __builtin_bit_cast(bf16x8,
                    *(const int4*)&Vs[d * 64 + ((slot ^ (d & 7)) << 3)]);
                accd[dt] = mfma32(pa, bv, accd[dt]);
            }
        }
    };

    // prologue: tile 0 into buffer 0
    stageP(0, ksr, vsr);
    ksr += 4096; vsr += 64;
    __syncthreads();

    // pair-unrolled loop: buffer0 = even tiles, buffer1 = odd tiles
    int t = 0;
    while (t + 1 <= qt) {
        // A: compute buffer0 (tile t), prefetch tile t+1 into buffer1
        stageP(1, ksr, vsr);
        ksr += 4096; vsr += 64;
        doTile(&Ksm[0][0], &Vsm[0][0], t);
        __syncthreads();
        // B: compute buffer1 (tile t+1), prefetch tile t+2 into buffer0
        if (t + 2 <= qt) {
            stageP(0, ksr, vsr);
            ksr += 4096; vsr += 64;
        }
        doTile(&Ksm[1][0], &Vsm[1][0], t + 1);
        __syncthreads();
        t += 2;
    }
    if (t <= qt) {                        // even qt tail: tile t in buffer0
        doTile(&Ksm[0][0], &Vsm[0][0], t);
        __syncthreads();
    }

    // ---- cross-wave (k-parity) reduce via LDS, then kp==0 writes Ctx
    float* red = (float*)&Ksm[0][0];      // 16KB: 2 q-halves x 8KB
    if (kp == 1) {
#pragma unroll
        for (int dt = 0; dt < 2; ++dt)
#pragma unroll
            for (int m2 = 0; m2 < 16; ++m2)
                red[qh * 2048 + (dt * 16 + m2) * 64 + lane] = accd[dt][m2];
    }
    __syncthreads();
    if (kp == 0) {
#pragma unroll
        for (int dt = 0; dt < 2; ++dt)
#pragma unroll
            for (int m2 = 0; m2 < 16; ++m2) {
                const float v = accd[dt][m2] + red[qh * 2048 + (dt * 16 + m2) * 64 + lane];
                const int q = qw + (m2 & 3) + 8 * (m2 >> 2) + 4 * hl;
                const int d = dt * 32 + l31;
                Ctx[(size_t)(b * SS + q) * DD + h * 64 + d] = __float2bfloat16(v);
            }
    }
}

// ---------------------------------------------------------------
extern "C" void kernel_launch(void* const* d_in, const int* in_sizes, int n_in,
                              void* d_out, int out_size, void* d_ws, size_t ws_size,
                              hipStream_t stream) {
    const float* X  = (const float*)d_in[0];
    const int* masks = (const int*)d_in[1];
    const float* Wq = (const float*)d_in[2];
    const float* Wk = (const float*)d_in[3];
    const float* Wv = (const float*)d_in[4];
    const float* Wo = (const float*)d_in[5];
    float* out = (float*)d_out;
    char* ws = (char*)d_ws;

    const size_t MB = 1024 * 1024;
    bf* Xb   = (bf*)(ws);              // 8 MB  [B*S, D]
    bf* Wqkv = (bf*)(ws + 8  * MB);    // 6 MB  [3072, 1024]
    bf* Wob  = (bf*)(ws + 14 * MB);    // 2 MB
    bf* Qn   = (bf*)(ws + 16 * MB);    // 8 MB  [B*H, S, 64]
    bf* Kn   = (bf*)(ws + 24 * MB);
    bf* Vt   = (bf*)(ws + 32 * MB);    // 8 MB  [B*H, 64, S]
    bf* Ctx  = (bf*)(ws + 40 * MB);    // 8 MB  [B*S, D]

    // converts (one launch)
    k_convert<<<8192, 256, 0, stream>>>(X, Wq, Wk, Wv, Wo, Xb, Wqkv, Wob);

    // fused QKV projection + norm/mask epilogue + V-transpose
    // (128x128 tiles -> 768 blocks, 8 waves, 3-buffer unrolled-x3)
    k_gemm8<<<(ND3 / 128) * (MMR / 128), 512, 0, stream>>>(
        Xb, Wqkv, masks, Qn, Kn, Vt, ND3 / 128);

    // attention (r14 VALU-lean pair-unrolled loop)
    k_attn<<<1024, 256, 0, stream>>>(Qn, Kn, Vt, Ctx);

    // output projection (64x128 tiles -> 512 blocks)
    k_gemm<<<(DD / 128) * (MMR / 64), 256, 0, stream>>>(
        Ctx, Wob, out, DD / 128, DD, DD);
}

// Round 17
// 94.361 us; speedup vs baseline: 1.3615x; 1.0053x over previous
//
#include <hip/hip_runtime.h>
#include <hip/hip_bf16.h>

// Problem constants
#define BB 2
#define SS 2048
#define DD 1024
#define HH 16
#define MMR (BB*SS)   // 4096 rows
#define ND3 3072      // fused QKV width

typedef __hip_bfloat16 bf;
typedef __bf16 bf16x8 __attribute__((ext_vector_type(8)));
typedef float f32x4 __attribute__((ext_vector_type(4)));
typedef float f32x16 __attribute__((ext_vector_type(16)));

#define VMCNT(n) asm volatile("s_waitcnt vmcnt(" #n ")" ::: "memory")

__device__ __forceinline__ f32x4 mfma16(bf16x8 a, bf16x8 b, f32x4 c) {
    return __builtin_amdgcn_mfma_f32_16x16x32_bf16(a, b, c, 0, 0, 0);
}
__device__ __forceinline__ f32x16 mfma32(bf16x8 a, bf16x8 b, f32x16 c) {
    return __builtin_amdgcn_mfma_f32_32x32x16_bf16(a, b, c, 0, 0, 0);
}
__device__ __forceinline__ unsigned cvt_pk_bf16(float lo, float hi) {
    unsigned r;
    asm("v_cvt_pk_bf16_f32 %0, %1, %2" : "=v"(r) : "v"(lo), "v"(hi));
    return r;
}
// after: a = {a.lo31, b.lo31}, b = {a.hi31, b.hi31}
__device__ __forceinline__ void pl32swap(unsigned& a, unsigned& b) {
    asm("v_permlane32_swap_b32 %0, %1" : "+v"(a), "+v"(b));
}
// async global->LDS, 16B/lane; LDS dest = wave-uniform base + lane*16
__device__ __forceinline__ void glds16(const bf* g, bf* l) {
    __builtin_amdgcn_global_load_lds(
        (const __attribute__((address_space(1))) void*)g,
        (__attribute__((address_space(3))) void*)l,
        16, 0, 0);
}

// ---------------------------------------------------------------
// All f32->bf16 converts in ONE launch. blocks 0..4095: X (4M elems);
// blocks 4096..8191: Wq,Wk,Wv (into Wqkv) and Wo (into Wob), 1M each.
__global__ __launch_bounds__(256) void k_convert(const float* __restrict__ X,
                                                 const float* __restrict__ Wq,
                                                 const float* __restrict__ Wk,
                                                 const float* __restrict__ Wv,
                                                 const float* __restrict__ Wo,
                                                 bf* __restrict__ Xb,
                                                 bf* __restrict__ Wqkv,
                                                 bf* __restrict__ Wob) {
    const int bid = blockIdx.x;
    const float* src;
    bf* dst;
    int off;
    if (bid < 4096) {
        src = X; dst = Xb; off = bid;
    } else {
        const int r = (bid - 4096) >> 10;
        src = (r == 0) ? Wq : (r == 1) ? Wk : (r == 2) ? Wv : Wo;
        dst = (r < 3) ? (Wqkv + (size_t)r * 1048576) : Wob;
        off = (bid - 4096) & 1023;
    }
    const int j = (off * 256 + threadIdx.x) * 4;
    float4 v = *(const float4*)(src + j);
    bf tmp[4];
    tmp[0] = __float2bfloat16(v.x);
    tmp[1] = __float2bfloat16(v.y);
    tmp[2] = __float2bfloat16(v.z);
    tmp[3] = __float2bfloat16(v.w);
    *(uint2*)(dst + j) = *(const uint2*)tmp;
}

// ---------------------------------------------------------------
// QKV GEMM v3 (r16-proven, ~37us): 3-buffer counted-vmcnt pipeline, K-loop
// unrolled x3 (compile-time buffer indices), running global source pointers.
// launch_bounds(512,6). Fused epilogue: per-head L2-norm*mask -> Qn/Kn;
// V cols -> transposed Vt. K fixed = 1024.
__global__ __launch_bounds__(512, 6) void k_gemm8(const bf* __restrict__ A,
                                                  const bf* __restrict__ Bt,
                                                  const int* __restrict__ masks,
                                                  bf* __restrict__ Qn,
                                                  bf* __restrict__ Kn,
                                                  bf* __restrict__ Vt,
                                                  int nx) {
    constexpr int K = 1024;
    constexpr int T = K >> 5;        // 32 K-steps
    __shared__ __align__(16) bf Asm[3][128 * 32];
    __shared__ __align__(16) bf Bsm[3][128 * 32];
    const int tid = threadIdx.x;
    const int w = tid >> 6, lane = tid & 63, g = lane >> 4, rl = lane & 15;
    const int cpx = gridDim.x >> 3;
    const int swz = (blockIdx.x & 7) * cpx + (blockIdx.x >> 3);
    const int m0 = (swz / nx) * 128, n0 = (swz % nx) * 128;
    const int wr = (w >> 1) * 32, wc = (w & 1) * 64;
    const int lrow = lane >> 2, lseg = lane & 3;
    const int xseg = lseg ^ ((lrow >> 1) & 3);   // pre-swizzled source seg

    f32x4 acc[2][4] = {};

    const bf* asr = A + (size_t)(m0 + w * 16 + lrow) * K + xseg * 8;
    const bf* bsr = Bt + (size_t)(n0 + w * 16 + lrow) * K + xseg * 8;
    bf* const adst = &Asm[0][w * 512];
    bf* const bdst = &Bsm[0][w * 512];

    auto stageP = [&](int buf) {     // buf is compile-time at every call site
        glds16(asr, adst + buf * 4096);
        glds16(bsr, bdst + buf * 4096);
        asr += 32; bsr += 32;
    };

    auto computeT = [&](const bf* Ab, const bf* Bb) {
        bf16x8 af[2], bfr[4];
#pragma unroll
        for (int m = 0; m < 2; ++m) {
            const int row = wr + m * 16 + rl;
            af[m] = __builtin_bit_cast(bf16x8,
                *(const int4*)&Ab[row * 32 + (g ^ ((row >> 1) & 3)) * 8]);
        }
#pragma unroll
        for (int n = 0; n < 4; ++n) {
            const int row = wc + n * 16 + rl;
            bfr[n] = __builtin_bit_cast(bf16x8,
                *(const int4*)&Bb[row * 32 + (g ^ ((row >> 1) & 3)) * 8]);
        }
        __builtin_amdgcn_s_setprio(1);
#pragma unroll
        for (int m = 0; m < 2; ++m)
#pragma unroll
            for (int n = 0; n < 4; ++n)
                acc[m][n] = mfma16(af[m], bfr[n], acc[m][n]);
        __builtin_amdgcn_s_setprio(0);
    };

    auto step = [&](auto CURc, auto NXTc, int t) {
        constexpr int CUR = decltype(CURc)::value;
        constexpr int NXT = decltype(NXTc)::value;
        __builtin_amdgcn_sched_barrier(0);
        if (t < T - 1) { VMCNT(2); } else { VMCNT(0); }
        __builtin_amdgcn_s_barrier();     // staged loads stay in flight
        __builtin_amdgcn_sched_barrier(0);
        if (t + 2 < T) stageP(NXT);
        computeT(&Asm[CUR][0], &Bsm[CUR][0]);
    };
    using c0 = std::integral_constant<int, 0>;
    using c1 = std::integral_constant<int, 1>;
    using c2 = std::integral_constant<int, 2>;

    stageP(0);
    stageP(1);
#pragma unroll 1
    for (int t = 0; t < 30; t += 3) {
        step(c0{}, c2{}, t);
        step(c1{}, c0{}, t + 1);
        step(c2{}, c1{}, t + 2);
    }
    step(c0{}, c2{}, 30);
    step(c1{}, c0{}, 31);

    const int ncol0 = n0 + wc;   // wave's 64-col base == one head slice
    if (ncol0 < 2048) {
        bf* dst = (ncol0 < 1024) ? Qn : Kn;
        const int h2 = (ncol0 >> 6) & 15;
#pragma unroll
        for (int m = 0; m < 2; ++m) {
#pragma unroll
            for (int ri = 0; ri < 4; ++ri) {
                const int row = m0 + wr + m * 16 + g * 4 + ri;   // b*S+s
                float ss = 0.f;
#pragma unroll
                for (int n = 0; n < 4; ++n) ss += acc[m][n][ri] * acc[m][n][ri];
#pragma unroll
                for (int d = 1; d < 16; d <<= 1) ss += __shfl_xor(ss, d, 64);
                const float sc = rsqrtf(ss) * (masks[row] ? 1.0f : 0.0f);
                const int b = row >> 11, s = row & 2047;
                const size_t base = ((size_t)(b * HH + h2) * SS + s) * 64;
#pragma unroll
                for (int n = 0; n < 4; ++n)
                    dst[base + n * 16 + rl] = __float2bfloat16(acc[m][n][ri] * sc);
            }
        }
    } else {
        // fused V transpose: Vt[(b*H+h)*64 + d][s], packed 4-bf16 writes
        const int h2 = (ncol0 - 2048) >> 6;
        const int b = (m0 + wr) >> 11;
        const int sb = ((m0 + wr) & 2047) + g * 4;
#pragma unroll
        for (int m = 0; m < 2; ++m)
#pragma unroll
            for (int n = 0; n < 4; ++n) {
                const int d = n * 16 + rl;
                bf t4[4];
#pragma unroll
                for (int ri = 0; ri < 4; ++ri) t4[ri] = __float2bfloat16(acc[m][n][ri]);
                *(uint2*)&Vt[((size_t)(b * HH + h2) * 64 + d) * SS + sb + m * 16] =
                    *(uint2*)t4;
            }
    }
}

// ---------------------------------------------------------------
// Out-proj GEMM: 64x128 tile, BK=32, 4 waves, 3-buffer counted-vmcnt pipeline.
__global__ __launch_bounds__(256) void k_gemm(const bf* __restrict__ A,
                                              const bf* __restrict__ Bt,
                                              float* __restrict__ Cf,
                                              int nx, int N, int K) {
    constexpr int BM = 64, BN = 128;
    __shared__ __align__(16) bf Asm[3][BM * 32];
    __shared__ __align__(16) bf Bsm[3][BN * 32];
    const int tid = threadIdx.x;
    const int w = tid >> 6, lane = tid & 63, g = lane >> 4, rl = lane & 15;
    const int cpx = gridDim.x >> 3;
    const int swz = (blockIdx.x & 7) * cpx + (blockIdx.x >> 3);
    const int m0 = (swz / nx) * BM, n0 = (swz % nx) * BN;
    const int wr = (w >> 1) * 32, wc = (w & 1) * 64;
    const int lrow = lane >> 2, lseg = lane & 3;
    const int xseg = lseg ^ ((lrow >> 1) & 3);

    f32x4 acc[2][4] = {};
    const bf* Ap = A + (size_t)m0 * K;
    const bf* Bp = Bt + (size_t)n0 * K;

    auto stage = [&](int bi, int k0) {
        glds16(Ap + (size_t)(w * 16 + lrow) * K + k0 + xseg * 8, &Asm[bi][w * 512]);
#pragma unroll
        for (int u = 0; u < 2; ++u)
            glds16(Bp + (size_t)(u * 64 + w * 16 + lrow) * K + k0 + xseg * 8,
                   &Bsm[bi][(u * 64 + w * 16) * 32]);
    };

    const int T = K >> 5;
    stage(0, 0);
    stage(1, 32);
    int cur = 0, nxt = 2;
    for (int t = 0; t < T; ++t) {
        __builtin_amdgcn_sched_barrier(0);
        if (t < T - 1) { VMCNT(3); } else { VMCNT(0); }
        __builtin_amdgcn_s_barrier();
        __builtin_amdgcn_sched_barrier(0);
        if (t + 2 < T) stage(nxt, (t + 2) * 32);

        const bf* Ab = Asm[cur];
        const bf* Bb = Bsm[cur];
        bf16x8 af[2], bfr[4];
#pragma unroll
        for (int m = 0; m < 2; ++m) {
            const int row = wr + m * 16 + rl;
            af[m] = __builtin_bit_cast(bf16x8,
                *(const int4*)&Ab[row * 32 + (g ^ ((row >> 1) & 3)) * 8]);
        }
#pragma unroll
        for (int n = 0; n < 4; ++n) {
            const int row = wc + n * 16 + rl;
            bfr[n] = __builtin_bit_cast(bf16x8,
                *(const int4*)&Bb[row * 32 + (g ^ ((row >> 1) & 3)) * 8]);
        }
        __builtin_amdgcn_s_setprio(1);
#pragma unroll
        for (int m = 0; m < 2; ++m)
#pragma unroll
            for (int n = 0; n < 4; ++n)
                acc[m][n] = mfma16(af[m], bfr[n], acc[m][n]);
        __builtin_amdgcn_s_setprio(0);

        cur = (cur == 2) ? 0 : cur + 1;
        nxt = (nxt == 2) ? 0 : nxt + 1;
    }

#pragma unroll
    for (int m = 0; m < 2; ++m)
#pragma unroll
        for (int n = 0; n < 4; ++n)
#pragma unroll
            for (int ri = 0; ri < 4; ++ri)
                Cf[(size_t)(m0 + wr + m * 16 + g * 4 + ri) * N + n0 + wc + n * 16 + rl] =
                    acc[m][n][ri];
}

// ---------------------------------------------------------------
// Attention v8: r14's proven per-wave body scaled to 8 WAVES (512 thr),
// q-tile 128 = 4 q-halves x 2 k-parities. Staging per wave halves (16
// chunks shared by 8 waves -> 2 glds16/tile/wave); 512 blocks x 2/CU x
// 8 waves = 16 waves/CU (was ~9). VGPR unchanged (one Q/acc set per wave
// -- NOT r8's 2x-reuse that doubled VGPR). Pair-unrolled compile-time
// buffers + running global pointers (r14). LPT: qt descending; blocks
// 0-255 heavy half, 256-511 light half -> each CU hosts one of each.
__global__ __launch_bounds__(512) void k_attn(const bf* __restrict__ Qn,  // [B*H,S,64]
                                              const bf* __restrict__ Kn,  // [B*H,S,64]
                                              const bf* __restrict__ Vt,  // [B*H,64,S]
                                              bf* __restrict__ Ctx) {     // [B*S, D]
    __shared__ __align__(16) bf smem[16384];      // 32KB: K[2][4096] | V[2][4096]
    bf* const Ksm0 = smem;
    bf* const Vsm0 = smem + 8192;

    const int idx = blockIdx.x;           // 512 blocks
    const int qt = 15 - (idx >> 5);       // 0..15 (128-row q-tiles), largest-first
    const int by = idx & 31;              // b*H + h
    const int b = by >> 4, h = by & 15;
    const int tid = threadIdx.x;
    const int w = tid >> 6, lane = tid & 63;
    const int l31 = lane & 31, hl = lane >> 5;
    const int qh = w >> 1;                // 0..3: q rows qt*128 + qh*32 ..+32
    const int kp = w & 1;                 // k-parity: subtile kb = t*64+kp*32
    const int qw = qt * 128 + qh * 32;
    const int qg = qw + l31;

    const bf* Qp = Qn + (size_t)by * SS * 64;
    const bf* Kp = Kn + (size_t)by * SS * 64;
    const bf* Vp = Vt + (size_t)by * 64 * SS;

    // hoisted Q (B-operand): col=q=l31, d = st*16 + hl*8 + 0..7
    bf16x8 aqs[4];
#pragma unroll
    for (int st = 0; st < 4; ++st)
        aqs[st] = __builtin_bit_cast(bf16x8,
            *(const int4*)(Qp + (size_t)(qw + l31) * 64 + st * 16 + hl * 8));

    // staging: 16 chunks (8 K + 8 V) over 8 waves -> wave w stages K-chunk w
    // and V-chunk w (chunk = 8 rows x 128B); pre-swizzled source slot
    const int srow = lane >> 3;
    const int sblk = (lane & 7) ^ srow;

    // running source pointers: tile t adds 4096 (K) / 64 (V)
    const bf* ksr = Kp + (size_t)(w * 8 + srow) * 64 + sblk * 8;
    const bf* vsr = Vp + (size_t)(w * 8 + srow) * SS + sblk * 8;
    bf* const kdst = Ksm0 + w * 512;
    bf* const vdst = Vsm0 + w * 512;

    auto stageP = [&](int buf) {          // buf compile-time at call sites
        glds16(ksr, kdst + buf * 4096);
        glds16(vsr, vdst + buf * 4096);
        ksr += 4096; vsr += 64;
    };

    f32x16 accd[2] = {};

    // per-tile compute (r14-verbatim body); Ks/Vs compile-time buffer bases
    auto doTile = [&](const bf* Ks, const bf* Vs, int t) {
        const int kb = t * 64 + kp * 32;
        if (kb > qw + 31) return;
        // ---- QK^T (swapped): D[row=k][col=q]
        f32x16 pc = {};
        const int r = kp * 32 + l31;
#pragma unroll
        for (int st = 0; st < 4; ++st) {
            bf16x8 ak = __builtin_bit_cast(bf16x8,
                *(const int4*)&Ks[r * 64 + (((2 * st + hl) ^ (r & 7)) << 3)]);
            pc = mfma32(ak, aqs[st], pc);
        }
        // ---- relu + causal (elementwise only near diagonal)
        const bool dg = (kb + 31 > qw);
        float pv[16];
#pragma unroll
        for (int m2 = 0; m2 < 16; ++m2) {
            float v = fmaxf(pc[m2], 0.0f);
            if (dg) {
                const int kg = kb + (m2 & 3) + 8 * (m2 >> 2) + 4 * hl;
                if (kg > qg) v = 0.0f;
            }
            pv[m2] = v;
        }
        // ---- pack to bf16 pairs + permlane swaps -> PV A-frags (no LDS)
        unsigned P[8];
#pragma unroll
        for (int m2 = 0; m2 < 8; ++m2) P[m2] = cvt_pk_bf16(pv[2 * m2], pv[2 * m2 + 1]);
        pl32swap(P[0], P[2]);
        pl32swap(P[1], P[3]);
        pl32swap(P[4], P[6]);
        pl32swap(P[5], P[7]);
        // ---- PV: D[row=q][col=d]
#pragma unroll
        for (int s = 0; s < 2; ++s) {
            uint4 pw = {P[4 * s + 0], P[4 * s + 1], P[4 * s + 2], P[4 * s + 3]};
            bf16x8 pa = __builtin_bit_cast(bf16x8, pw);
#pragma unroll
            for (int dt = 0; dt < 2; ++dt) {
                const int d = dt * 32 + l31;
                const int slot = kp * 4 + s * 2 + hl;
                bf16x8 bv = __builtin_bit_cast(bf16x8,
                    *(const int4*)&Vs[d * 64 + ((slot ^ (d & 7)) << 3)]);
                accd[dt] = mfma32(pa, bv, accd[dt]);
            }
        }
    };

    // prologue: tile 0 into buffer 0
    stageP(0);
    __syncthreads();

    // pair-unrolled loop: buffer0 = even tiles, buffer1 = odd tiles.
    // nt = 2*qt + 2 (always even -> no tail).
    const int nt = 2 * qt + 2;
    int t = 0;
    while (t + 1 < nt) {
        stageP(1);                               // tile t+1 -> buf1
        doTile(Ksm0, Vsm0, t);
        __syncthreads();
        if (t + 2 < nt) stageP(0);               // tile t+2 -> buf0
        doTile(Ksm0 + 4096, Vsm0 + 4096, t + 1);
        __syncthreads();
        t += 2;
    }

    // ---- cross-wave (k-parity) reduce via LDS (32KB: [4 qh][32 q][64 d]),
    // then kp==0 writes Ctx
    float* red = (float*)smem;
    if (kp == 1) {
#pragma unroll
        for (int dt = 0; dt < 2; ++dt)
#pragma unroll
            for (int m2 = 0; m2 < 16; ++m2)
                red[qh * 2048 + (dt * 16 + m2) * 64 + lane] = accd[dt][m2];
    }
    __syncthreads();
    if (kp == 0) {
#pragma unroll
        for (int dt = 0; dt < 2; ++dt)
#pragma unroll
            for (int m2 = 0; m2 < 16; ++m2) {
                const float v = accd[dt][m2] + red[qh * 2048 + (dt * 16 + m2) * 64 + lane];
                const int q = qw + (m2 & 3) + 8 * (m2 >> 2) + 4 * hl;
                const int d = dt * 32 + l31;
                Ctx[(size_t)(b * SS + q) * DD + h * 64 + d] = __float2bfloat16(v);
            }
    }
}

// ---------------------------------------------------------------
extern "C" void kernel_launch(void* const* d_in, const int* in_sizes, int n_in,
                              void* d_out, int out_size, void* d_ws, size_t ws_size,
                              hipStream_t stream) {
    const float* X  = (const float*)d_in[0];
    const int* masks = (const int*)d_in[1];
    const float* Wq = (const float*)d_in[2];
    const float* Wk = (const float*)d_in[3];
    const float* Wv = (const float*)d_in[4];
    const float* Wo = (const float*)d_in[5];
    float* out = (float*)d_out;
    char* ws = (char*)d_ws;

    const size_t MB = 1024 * 1024;
    bf* Xb   = (bf*)(ws);              // 8 MB  [B*S, D]
    bf* Wqkv = (bf*)(ws + 8  * MB);    // 6 MB  [3072, 1024]
    bf* Wob  = (bf*)(ws + 14 * MB);    // 2 MB
    bf* Qn   = (bf*)(ws + 16 * MB);    // 8 MB  [B*H, S, 64]
    bf* Kn   = (bf*)(ws + 24 * MB);
    bf* Vt   = (bf*)(ws + 32 * MB);    // 8 MB  [B*H, 64, S]
    bf* Ctx  = (bf*)(ws + 40 * MB);    // 8 MB  [B*S, D]

    // converts (one launch)
    k_convert<<<8192, 256, 0, stream>>>(X, Wq, Wk, Wv, Wo, Xb, Wqkv, Wob);

    // fused QKV projection + norm/mask epilogue + V-transpose
    // (128x128 tiles -> 768 blocks, 8 waves, 3-buffer unrolled-x3)
    k_gemm8<<<(ND3 / 128) * (MMR / 128), 512, 0, stream>>>(
        Xb, Wqkv, masks, Qn, Kn, Vt, ND3 / 128);

    // attention (8-wave q-tile-128, 512 blocks)
    k_attn<<<512, 512, 0, stream>>>(Qn, Kn, Vt, Ctx);

    // output projection (64x128 tiles -> 512 blocks)
    k_gemm<<<(DD / 128) * (MMR / 64), 256, 0, stream>>>(
        Ctx, Wob, out, DD / 128, DD, DD);
}

// Round 18
// 93.313 us; speedup vs baseline: 1.3768x; 1.0112x over previous
//
#include <hip/hip_runtime.h>
#include <hip/hip_bf16.h>

// Problem constants
#define BB 2
#define SS 2048
#define DD 1024
#define HH 16
#define MMR (BB*SS)   // 4096 rows
#define ND3 3072      // fused QKV width

typedef __hip_bfloat16 bf;
typedef __bf16 bf16x8 __attribute__((ext_vector_type(8)));
typedef float f32x4 __attribute__((ext_vector_type(4)));
typedef float f32x16 __attribute__((ext_vector_type(16)));

#define VMCNT(n) asm volatile("s_waitcnt vmcnt(" #n ")" ::: "memory")

__device__ __forceinline__ f32x4 mfma16(bf16x8 a, bf16x8 b, f32x4 c) {
    return __builtin_amdgcn_mfma_f32_16x16x32_bf16(a, b, c, 0, 0, 0);
}
__device__ __forceinline__ f32x16 mfma32(bf16x8 a, bf16x8 b, f32x16 c) {
    return __builtin_amdgcn_mfma_f32_32x32x16_bf16(a, b, c, 0, 0, 0);
}
__device__ __forceinline__ unsigned cvt_pk_bf16(float lo, float hi) {
    unsigned r;
    asm("v_cvt_pk_bf16_f32 %0, %1, %2" : "=v"(r) : "v"(lo), "v"(hi));
    return r;
}
// after: a = {a.lo31, b.lo31}, b = {a.hi31, b.hi31}
__device__ __forceinline__ void pl32swap(unsigned& a, unsigned& b) {
    asm("v_permlane32_swap_b32 %0, %1" : "+v"(a), "+v"(b));
}
// async global->LDS, 16B/lane; LDS dest = wave-uniform base + lane*16
__device__ __forceinline__ void glds16(const bf* g, bf* l) {
    __builtin_amdgcn_global_load_lds(
        (const __attribute__((address_space(1))) void*)g,
        (__attribute__((address_space(3))) void*)l,
        16, 0, 0);
}

// ---------------------------------------------------------------
// All f32->bf16 converts in ONE launch. blocks 0..4095: X (4M elems);
// blocks 4096..8191: Wq,Wk,Wv (into Wqkv) and Wo (into Wob), 1M each.
__global__ __launch_bounds__(256) void k_convert(const float* __restrict__ X,
                                                 const float* __restrict__ Wq,
                                                 const float* __restrict__ Wk,
                                                 const float* __restrict__ Wv,
                                                 const float* __restrict__ Wo,
                                                 bf* __restrict__ Xb,
                                                 bf* __restrict__ Wqkv,
                                                 bf* __restrict__ Wob) {
    const int bid = blockIdx.x;
    const float* src;
    bf* dst;
    int off;
    if (bid < 4096) {
        src = X; dst = Xb; off = bid;
    } else {
        const int r = (bid - 4096) >> 10;
        src = (r == 0) ? Wq : (r == 1) ? Wk : (r == 2) ? Wv : Wo;
        dst = (r < 3) ? (Wqkv + (size_t)r * 1048576) : Wob;
        off = (bid - 4096) & 1023;
    }
    const int j = (off * 256 + threadIdx.x) * 4;
    float4 v = *(const float4*)(src + j);
    bf tmp[4];
    tmp[0] = __float2bfloat16(v.x);
    tmp[1] = __float2bfloat16(v.y);
    tmp[2] = __float2bfloat16(v.z);
    tmp[3] = __float2bfloat16(v.w);
    *(uint2*)(dst + j) = *(const uint2*)tmp;
}

// ---------------------------------------------------------------
// QKV GEMM v3 (r16-proven, ~37us): 3-buffer counted-vmcnt pipeline, K-loop
// unrolled x3 (compile-time buffer indices), running global source pointers.
// launch_bounds(512,6). Fused epilogue: per-head L2-norm*mask -> Qn/Kn;
// V cols -> transposed Vt. K fixed = 1024.
__global__ __launch_bounds__(512, 6) void k_gemm8(const bf* __restrict__ A,
                                                  const bf* __restrict__ Bt,
                                                  const int* __restrict__ masks,
                                                  bf* __restrict__ Qn,
                                                  bf* __restrict__ Kn,
                                                  bf* __restrict__ Vt,
                                                  int nx) {
    constexpr int K = 1024;
    constexpr int T = K >> 5;        // 32 K-steps
    __shared__ __align__(16) bf Asm[3][128 * 32];
    __shared__ __align__(16) bf Bsm[3][128 * 32];
    const int tid = threadIdx.x;
    const int w = tid >> 6, lane = tid & 63, g = lane >> 4, rl = lane & 15;
    const int cpx = gridDim.x >> 3;
    const int swz = (blockIdx.x & 7) * cpx + (blockIdx.x >> 3);
    const int m0 = (swz / nx) * 128, n0 = (swz % nx) * 128;
    const int wr = (w >> 1) * 32, wc = (w & 1) * 64;
    const int lrow = lane >> 2, lseg = lane & 3;
    const int xseg = lseg ^ ((lrow >> 1) & 3);   // pre-swizzled source seg

    f32x4 acc[2][4] = {};

    const bf* asr = A + (size_t)(m0 + w * 16 + lrow) * K + xseg * 8;
    const bf* bsr = Bt + (size_t)(n0 + w * 16 + lrow) * K + xseg * 8;
    bf* const adst = &Asm[0][w * 512];
    bf* const bdst = &Bsm[0][w * 512];

    auto stageP = [&](int buf) {     // buf is compile-time at every call site
        glds16(asr, adst + buf * 4096);
        glds16(bsr, bdst + buf * 4096);
        asr += 32; bsr += 32;
    };

    auto computeT = [&](const bf* Ab, const bf* Bb) {
        bf16x8 af[2], bfr[4];
#pragma unroll
        for (int m = 0; m < 2; ++m) {
            const int row = wr + m * 16 + rl;
            af[m] = __builtin_bit_cast(bf16x8,
                *(const int4*)&Ab[row * 32 + (g ^ ((row >> 1) & 3)) * 8]);
        }
#pragma unroll
        for (int n = 0; n < 4; ++n) {
            const int row = wc + n * 16 + rl;
            bfr[n] = __builtin_bit_cast(bf16x8,
                *(const int4*)&Bb[row * 32 + (g ^ ((row >> 1) & 3)) * 8]);
        }
        __builtin_amdgcn_s_setprio(1);
#pragma unroll
        for (int m = 0; m < 2; ++m)
#pragma unroll
            for (int n = 0; n < 4; ++n)
                acc[m][n] = mfma16(af[m], bfr[n], acc[m][n]);
        __builtin_amdgcn_s_setprio(0);
    };

    auto step = [&](auto CURc, auto NXTc, int t) {
        constexpr int CUR = decltype(CURc)::value;
        constexpr int NXT = decltype(NXTc)::value;
        __builtin_amdgcn_sched_barrier(0);
        if (t < T - 1) { VMCNT(2); } else { VMCNT(0); }
        __builtin_amdgcn_s_barrier();     // staged loads stay in flight
        __builtin_amdgcn_sched_barrier(0);
        if (t + 2 < T) stageP(NXT);
        computeT(&Asm[CUR][0], &Bsm[CUR][0]);
    };
    using c0 = std::integral_constant<int, 0>;
    using c1 = std::integral_constant<int, 1>;
    using c2 = std::integral_constant<int, 2>;

    stageP(0);
    stageP(1);
#pragma unroll 1
    for (int t = 0; t < 30; t += 3) {
        step(c0{}, c2{}, t);
        step(c1{}, c0{}, t + 1);
        step(c2{}, c1{}, t + 2);
    }
    step(c0{}, c2{}, 30);
    step(c1{}, c0{}, 31);

    const int ncol0 = n0 + wc;   // wave's 64-col base == one head slice
    if (ncol0 < 2048) {
        bf* dst = (ncol0 < 1024) ? Qn : Kn;
        const int h2 = (ncol0 >> 6) & 15;
#pragma unroll
        for (int m = 0; m < 2; ++m) {
#pragma unroll
            for (int ri = 0; ri < 4; ++ri) {
                const int row = m0 + wr + m * 16 + g * 4 + ri;   // b*S+s
                float ss = 0.f;
#pragma unroll
                for (int n = 0; n < 4; ++n) ss += acc[m][n][ri] * acc[m][n][ri];
#pragma unroll
                for (int d = 1; d < 16; d <<= 1) ss += __shfl_xor(ss, d, 64);
                const float sc = rsqrtf(ss) * (masks[row] ? 1.0f : 0.0f);
                const int b = row >> 11, s = row & 2047;
                const size_t base = ((size_t)(b * HH + h2) * SS + s) * 64;
#pragma unroll
                for (int n = 0; n < 4; ++n)
                    dst[base + n * 16 + rl] = __float2bfloat16(acc[m][n][ri] * sc);
            }
        }
    } else {
        // fused V transpose: Vt[(b*H+h)*64 + d][s], packed 4-bf16 writes
        const int h2 = (ncol0 - 2048) >> 6;
        const int b = (m0 + wr) >> 11;
        const int sb = ((m0 + wr) & 2047) + g * 4;
#pragma unroll
        for (int m = 0; m < 2; ++m)
#pragma unroll
            for (int n = 0; n < 4; ++n) {
                const int d = n * 16 + rl;
                bf t4[4];
#pragma unroll
                for (int ri = 0; ri < 4; ++ri) t4[ri] = __float2bfloat16(acc[m][n][ri]);
                *(uint2*)&Vt[((size_t)(b * HH + h2) * 64 + d) * SS + sb + m * 16] =
                    *(uint2*)t4;
            }
    }
}

// ---------------------------------------------------------------
// Out-proj GEMM v2: 64x128 tile, BK=32, 4 waves; r16's unroll-x3 treatment
// (compile-time mod-3 buffer indices, running global source pointers).
// K fixed = 1024, N fixed = 1024. VMCNT(3) counted waits (3 loads/thr/stage).
__global__ __launch_bounds__(256) void k_gemm(const bf* __restrict__ A,
                                              const bf* __restrict__ Bt,
                                              float* __restrict__ Cf,
                                              int nx) {
    constexpr int BM = 64, BN = 128;
    constexpr int K = 1024, N = 1024;
    constexpr int T = K >> 5;        // 32 K-steps
    __shared__ __align__(16) bf Asm[3][BM * 32];
    __shared__ __align__(16) bf Bsm[3][BN * 32];
    const int tid = threadIdx.x;
    const int w = tid >> 6, lane = tid & 63, g = lane >> 4, rl = lane & 15;
    const int cpx = gridDim.x >> 3;
    const int swz = (blockIdx.x & 7) * cpx + (blockIdx.x >> 3);
    const int m0 = (swz / nx) * BM, n0 = (swz % nx) * BN;
    const int wr = (w >> 1) * 32, wc = (w & 1) * 64;
    const int lrow = lane >> 2, lseg = lane & 3;
    const int xseg = lseg ^ ((lrow >> 1) & 3);

    f32x4 acc[2][4] = {};

    // running source pointers: +32 elems per K-step; B chunk u=1 at +64*K
    const bf* asr = A + (size_t)(m0 + w * 16 + lrow) * K + xseg * 8;
    const bf* bsr = Bt + (size_t)(n0 + w * 16 + lrow) * K + xseg * 8;
    bf* const adst = &Asm[0][w * 512];
    bf* const bdst = &Bsm[0][w * 512];

    auto stageP = [&](int buf) {     // buf compile-time at every call site
        glds16(asr, adst + buf * 2048);
        glds16(bsr, bdst + buf * 4096);
        glds16(bsr + 64 * K, bdst + buf * 4096 + 2048);
        asr += 32; bsr += 32;
    };

    auto computeT = [&](const bf* Ab, const bf* Bb) {
        bf16x8 af[2], bfr[4];
#pragma unroll
        for (int m = 0; m < 2; ++m) {
            const int row = wr + m * 16 + rl;
            af[m] = __builtin_bit_cast(bf16x8,
                *(const int4*)&Ab[row * 32 + (g ^ ((row >> 1) & 3)) * 8]);
        }
#pragma unroll
        for (int n = 0; n < 4; ++n) {
            const int row = wc + n * 16 + rl;
            bfr[n] = __builtin_bit_cast(bf16x8,
                *(const int4*)&Bb[row * 32 + (g ^ ((row >> 1) & 3)) * 8]);
        }
        __builtin_amdgcn_s_setprio(1);
#pragma unroll
        for (int m = 0; m < 2; ++m)
#pragma unroll
            for (int n = 0; n < 4; ++n)
                acc[m][n] = mfma16(af[m], bfr[n], acc[m][n]);
        __builtin_amdgcn_s_setprio(0);
    };

    auto step = [&](auto CURc, auto NXTc, int t) {
        constexpr int CUR = decltype(CURc)::value;
        constexpr int NXT = decltype(NXTc)::value;
        __builtin_amdgcn_sched_barrier(0);
        if (t < T - 1) { VMCNT(3); } else { VMCNT(0); }
        __builtin_amdgcn_s_barrier();
        __builtin_amdgcn_sched_barrier(0);
        if (t + 2 < T) stageP(NXT);
        computeT(&Asm[CUR][0], &Bsm[CUR][0]);
    };
    using c0 = std::integral_constant<int, 0>;
    using c1 = std::integral_constant<int, 1>;
    using c2 = std::integral_constant<int, 2>;

    stageP(0);
    stageP(1);
#pragma unroll 1
    for (int t = 0; t < 30; t += 3) {
        step(c0{}, c2{}, t);
        step(c1{}, c0{}, t + 1);
        step(c2{}, c1{}, t + 2);
    }
    step(c0{}, c2{}, 30);
    step(c1{}, c0{}, 31);

#pragma unroll
    for (int m = 0; m < 2; ++m)
#pragma unroll
        for (int n = 0; n < 4; ++n)
#pragma unroll
            for (int ri = 0; ri < 4; ++ri)
                Cf[(size_t)(m0 + wr + m * 16 + g * 4 + ri) * N + n0 + wc + n * 16 + rl] =
                    acc[m][n][ri];
}

// ---------------------------------------------------------------
// Attention v8 (r17, best): r14's per-wave body at 8 waves (512 thr),
// q-tile 128 = 4 q-halves x 2 k-parities; 2 glds16/tile/wave; pair-unrolled
// compile-time buffers + running global pointers; in-register P via cvt_pk +
// permlane32_swap; kp-partials summed via one-time LDS reduce.
__global__ __launch_bounds__(512) void k_attn(const bf* __restrict__ Qn,  // [B*H,S,64]
                                              const bf* __restrict__ Kn,  // [B*H,S,64]
                                              const bf* __restrict__ Vt,  // [B*H,64,S]
                                              bf* __restrict__ Ctx) {     // [B*S, D]
    __shared__ __align__(16) bf smem[16384];      // 32KB: K[2][4096] | V[2][4096]
    bf* const Ksm0 = smem;
    bf* const Vsm0 = smem + 8192;

    const int idx = blockIdx.x;           // 512 blocks
    const int qt = 15 - (idx >> 5);       // 0..15 (128-row q-tiles), largest-first
    const int by = idx & 31;              // b*H + h
    const int b = by >> 4, h = by & 15;
    const int tid = threadIdx.x;
    const int w = tid >> 6, lane = tid & 63;
    const int l31 = lane & 31, hl = lane >> 5;
    const int qh = w >> 1;                // 0..3: q rows qt*128 + qh*32 ..+32
    const int kp = w & 1;                 // k-parity: subtile kb = t*64+kp*32
    const int qw = qt * 128 + qh * 32;
    const int qg = qw + l31;

    const bf* Qp = Qn + (size_t)by * SS * 64;
    const bf* Kp = Kn + (size_t)by * SS * 64;
    const bf* Vp = Vt + (size_t)by * 64 * SS;

    // hoisted Q (B-operand): col=q=l31, d = st*16 + hl*8 + 0..7
    bf16x8 aqs[4];
#pragma unroll
    for (int st = 0; st < 4; ++st)
        aqs[st] = __builtin_bit_cast(bf16x8,
            *(const int4*)(Qp + (size_t)(qw + l31) * 64 + st * 16 + hl * 8));

    // staging: 16 chunks (8 K + 8 V) over 8 waves; pre-swizzled source slot
    const int srow = lane >> 3;
    const int sblk = (lane & 7) ^ srow;

    // running source pointers: tile t adds 4096 (K) / 64 (V)
    const bf* ksr = Kp + (size_t)(w * 8 + srow) * 64 + sblk * 8;
    const bf* vsr = Vp + (size_t)(w * 8 + srow) * SS + sblk * 8;
    bf* const kdst = Ksm0 + w * 512;
    bf* const vdst = Vsm0 + w * 512;

    auto stageP = [&](int buf) {          // buf compile-time at call sites
        glds16(ksr, kdst + buf * 4096);
        glds16(vsr, vdst + buf * 4096);
        ksr += 4096; vsr += 64;
    };

    f32x16 accd[2] = {};

    // per-tile compute (r14-verbatim body); Ks/Vs compile-time buffer bases
    auto doTile = [&](const bf* Ks, const bf* Vs, int t) {
        const int kb = t * 64 + kp * 32;
        if (kb > qw + 31) return;
        // ---- QK^T (swapped): D[row=k][col=q]
        f32x16 pc = {};
        const int r = kp * 32 + l31;
#pragma unroll
        for (int st = 0; st < 4; ++st) {
            bf16x8 ak = __builtin_bit_cast(bf16x8,
                *(const int4*)&Ks[r * 64 + (((2 * st + hl) ^ (r & 7)) << 3)]);
            pc = mfma32(ak, aqs[st], pc);
        }
        // ---- relu + causal (elementwise only near diagonal)
        const bool dg = (kb + 31 > qw);
        float pv[16];
#pragma unroll
        for (int m2 = 0; m2 < 16; ++m2) {
            float v = fmaxf(pc[m2], 0.0f);
            if (dg) {
                const int kg = kb + (m2 & 3) + 8 * (m2 >> 2) + 4 * hl;
                if (kg > qg) v = 0.0f;
            }
            pv[m2] = v;
        }
        // ---- pack to bf16 pairs + permlane swaps -> PV A-frags (no LDS)
        unsigned P[8];
#pragma unroll
        for (int m2 = 0; m2 < 8; ++m2) P[m2] = cvt_pk_bf16(pv[2 * m2], pv[2 * m2 + 1]);
        pl32swap(P[0], P[2]);
        pl32swap(P[1], P[3]);
        pl32swap(P[4], P[6]);
        pl32swap(P[5], P[7]);
        // ---- PV: D[row=q][col=d]
#pragma unroll
        for (int s = 0; s < 2; ++s) {
            uint4 pw = {P[4 * s + 0], P[4 * s + 1], P[4 * s + 2], P[4 * s + 3]};
            bf16x8 pa = __builtin_bit_cast(bf16x8, pw);
#pragma unroll
            for (int dt = 0; dt < 2; ++dt) {
                const int d = dt * 32 + l31;
                const int slot = kp * 4 + s * 2 + hl;
                bf16x8 bv = __builtin_bit_cast(bf16x8,
                    *(const int4*)&Vs[d * 64 + ((slot ^ (d & 7)) << 3)]);
                accd[dt] = mfma32(pa, bv, accd[dt]);
            }
        }
    };

    // prologue: tile 0 into buffer 0
    stageP(0);
    __syncthreads();

    // pair-unrolled loop: buffer0 = even tiles, buffer1 = odd tiles.
    // nt = 2*qt + 2 (always even -> no tail).
    const int nt = 2 * qt + 2;
    int t = 0;
    while (t + 1 < nt) {
        stageP(1);                               // tile t+1 -> buf1
        doTile(Ksm0, Vsm0, t);
        __syncthreads();
        if (t + 2 < nt) stageP(0);               // tile t+2 -> buf0
        doTile(Ksm0 + 4096, Vsm0 + 4096, t + 1);
        __syncthreads();
        t += 2;
    }

    // ---- cross-wave (k-parity) reduce via LDS (32KB: [4 qh][32 q][64 d]),
    // then kp==0 writes Ctx
    float* red = (float*)smem;
    if (kp == 1) {
#pragma unroll
        for (int dt = 0; dt < 2; ++dt)
#pragma unroll
            for (int m2 = 0; m2 < 16; ++m2)
                red[qh * 2048 + (dt * 16 + m2) * 64 + lane] = accd[dt][m2];
    }
    __syncthreads();
    if (kp == 0) {
#pragma unroll
        for (int dt = 0; dt < 2; ++dt)
#pragma unroll
            for (int m2 = 0; m2 < 16; ++m2) {
                const float v = accd[dt][m2] + red[qh * 2048 + (dt * 16 + m2) * 64 + lane];
                const int q = qw + (m2 & 3) + 8 * (m2 >> 2) + 4 * hl;
                const int d = dt * 32 + l31;
                Ctx[(size_t)(b * SS + q) * DD + h * 64 + d] = __float2bfloat16(v);
            }
    }
}

// ---------------------------------------------------------------
extern "C" void kernel_launch(void* const* d_in, const int* in_sizes, int n_in,
                              void* d_out, int out_size, void* d_ws, size_t ws_size,
                              hipStream_t stream) {
    const float* X  = (const float*)d_in[0];
    const int* masks = (const int*)d_in[1];
    const float* Wq = (const float*)d_in[2];
    const float* Wk = (const float*)d_in[3];
    const float* Wv = (const float*)d_in[4];
    const float* Wo = (const float*)d_in[5];
    float* out = (float*)d_out;
    char* ws = (char*)d_ws;

    const size_t MB = 1024 * 1024;
    bf* Xb   = (bf*)(ws);              // 8 MB  [B*S, D]
    bf* Wqkv = (bf*)(ws + 8  * MB);    // 6 MB  [3072, 1024]
    bf* Wob  = (bf*)(ws + 14 * MB);    // 2 MB
    bf* Qn   = (bf*)(ws + 16 * MB);    // 8 MB  [B*H, S, 64]
    bf* Kn   = (bf*)(ws + 24 * MB);
    bf* Vt   = (bf*)(ws + 32 * MB);    // 8 MB  [B*H, 64, S]
    bf* Ctx  = (bf*)(ws + 40 * MB);    // 8 MB  [B*S, D]

    // converts (one launch)
    k_convert<<<8192, 256, 0, stream>>>(X, Wq, Wk, Wv, Wo, Xb, Wqkv, Wob);

    // fused QKV projection + norm/mask epilogue + V-transpose
    // (128x128 tiles -> 768 blocks, 8 waves, 3-buffer unrolled-x3)
    k_gemm8<<<(ND3 / 128) * (MMR / 128), 512, 0, stream>>>(
        Xb, Wqkv, masks, Qn, Kn, Vt, ND3 / 128);

    // attention (8-wave q-tile-128, 512 blocks)
    k_attn<<<512, 512, 0, stream>>>(Qn, Kn, Vt, Ctx);

    // output projection (64x128 tiles -> 512 blocks, unrolled-x3)
    k_gemm<<<(DD / 128) * (MMR / 64), 256, 0, stream>>>(
        Ctx, Wob, out, DD / 128);
}